// Round 7
// baseline (26.465 us; speedup 1.0000x reference)
//
#include <hip/hip_runtime.h>
#include <math.h>

constexpr int TLEN = 512;
constexpr int CDIM = 64;
constexpr int BDIM = 2;

// Phase 1: hkt4[(b*16 + c4)*512 + t] = float4 over c = 4*c4..4*c4+3 of
// hk[b,t,c] = sum_d x1[b,t,d] * W1[c,d].
// 64 blocks x 256 threads; thread = (c4 = tid>>4, tl = tid&15), 16 rows/block.
__global__ __launch_bounds__(256) void hk_kernel(
    const float* __restrict__ x, const float* __restrict__ pos,
    const float* __restrict__ W1, float4* __restrict__ hkt4)
{
    const int tid = threadIdx.x;
    const int c4  = tid >> 4;                 // 0..15
    const int tl  = tid & 15;                 // 0..15
    const int r0  = blockIdx.x * 16;          // global row base (b*512+t), 0..1023

    __shared__ float x1s[16][132];            // +4 pad: kills 16-way bank conflict
    #pragma unroll
    for (int e = tid; e < 16 * 128; e += 256) {
        const int r = e >> 7, d = e & 127;
        const int grow = r0 + r;
        const int tt = grow & (TLEN - 1);
        x1s[r][d] = (d < CDIM) ? pos[tt * CDIM + d]
                               : x[grow * CDIM + (d - CDIM)];
    }
    __syncthreads();

    const int grow = r0 + tl;
    const int b    = grow >> 9;
    const int tt   = grow & (TLEN - 1);

    float4 res;
    float* resp = (float*)&res;
    #pragma unroll
    for (int k = 0; k < 4; ++k) {
        const int c = c4 * 4 + k;
        const float4* w = (const float4*)(W1 + c * 256);   // Wk row c
        float4 a = make_float4(0.f, 0.f, 0.f, 0.f);
        #pragma unroll 8
        for (int d4 = 0; d4 < 32; ++d4) {
            const float4 xx = *(const float4*)&x1s[tl][d4 * 4];
            const float4 ww = w[d4];
            a.x = fmaf(xx.x, ww.x, a.x); a.y = fmaf(xx.y, ww.y, a.y);
            a.z = fmaf(xx.z, ww.z, a.z); a.w = fmaf(xx.w, ww.w, a.w);
        }
        resp[k] = (a.x + a.y) + (a.z + a.w);
    }
    hkt4[(b * 16 + c4) * TLEN + tt] = res;
}

// Phase 2: one block per row-pair (iA, 511-iA). Both rows processed in ONE
// pass: shared hkt loads for both scores, per-wave softmax stats (1 barrier),
// shared x loads for both PV accumulations.
__global__ __launch_bounds__(512) void attn_kernel(
    const float* __restrict__ x,  const float* __restrict__ pos,
    const float* __restrict__ W1, const float* __restrict__ b1,
    const float* __restrict__ W2, const float* __restrict__ b2,
    const float* __restrict__ Wv, const float4* __restrict__ hkt4,
    float* __restrict__ out)
{
    const int tid = threadIdx.x;
    const int idx = blockIdx.x;               // 0..511, heavy (small iA) first
    const int b   = idx & 1;
    const int iA  = idx >> 1;                 // 0..255
    const int iB  = (TLEN - 1) - iA;          // 256..511

    __shared__ alignas(16) float x1s[2][128];
    __shared__ float hqp[2][CDIM][4];
    __shared__ alignas(16) float hq_sf[2][CDIM];
    __shared__ float4 w24_s[16];
    __shared__ alignas(16) float pA[TLEN];
    __shared__ alignas(16) float pB[TLEN];
    __shared__ float4 wred4[8];               // per-wave {mA, sumA, mB, sumB}
    __shared__ float pvs[2][8][CDIM];
    __shared__ alignas(16) float o_s[2][CDIM];

    // stage x1 for both rows + W2
    if (tid < 256) {
        const int rp = tid >> 7, d = tid & 127;
        const int i  = rp ? iB : iA;
        const int r  = b * TLEN + i;
        x1s[rp][d] = (d < CDIM) ? pos[i * CDIM + d] : x[r * CDIM + (d - CDIM)];
    } else if (tid < 272) {
        w24_s[tid - 256] = ((const float4*)W2)[tid - 256];
    }
    __syncthreads();

    // hq partials: 512 threads, 8-f4 chains
    {
        const int rp = tid >> 8, c = (tid >> 2) & 63, part = tid & 3;
        const float4* wq = (const float4*)(W1 + c * 256 + 128) + part * 8;
        const float4* xv = ((const float4*)x1s[rp]) + part * 8;
        float4 a = make_float4(0.f, 0.f, 0.f, 0.f);
        #pragma unroll
        for (int d4 = 0; d4 < 8; ++d4) {
            const float4 xx = xv[d4];
            const float4 ww = wq[d4];
            a.x = fmaf(xx.x, ww.x, a.x); a.y = fmaf(xx.y, ww.y, a.y);
            a.z = fmaf(xx.z, ww.z, a.z); a.w = fmaf(xx.w, ww.w, a.w);
        }
        hqp[rp][c][part] = (a.x + a.y) + (a.z + a.w);
    }
    __syncthreads();
    if (tid < 128) {
        const int rp = tid >> 6, c = tid & 63;
        hq_sf[rp][c] = hqp[rp][c][0] + hqp[rp][c][1] + hqp[rp][c][2]
                     + hqp[rp][c][3] + b1[c];
    }
    __syncthreads();

    // ---- scores for BOTH rows, shared hkt loads ----
    const float b2v = b2[0];
    const float4* hk4b = hkt4 + b * 16 * TLEN;
    const float4* qA4  = (const float4*)hq_sf[0];
    const float4* qB4  = (const float4*)hq_sf[1];
    const int j = tid;

    float4 aA = make_float4(0.f, 0.f, 0.f, 0.f);
    float4 aB = make_float4(0.f, 0.f, 0.f, 0.f);
    #pragma unroll 4
    for (int c4 = 0; c4 < 16; ++c4) {
        const float4 kk = hk4b[c4 * TLEN + j];     // 16B/lane coalesced
        const float4 qa = qA4[c4];
        const float4 qb = qB4[c4];
        const float4 ww = w24_s[c4];
        aA.x = fmaf(fmaxf(kk.x + qa.x, 0.f), ww.x, aA.x);
        aA.y = fmaf(fmaxf(kk.y + qa.y, 0.f), ww.y, aA.y);
        aA.z = fmaf(fmaxf(kk.z + qa.z, 0.f), ww.z, aA.z);
        aA.w = fmaf(fmaxf(kk.w + qa.w, 0.f), ww.w, aA.w);
        aB.x = fmaf(fmaxf(kk.x + qb.x, 0.f), ww.x, aB.x);
        aB.y = fmaf(fmaxf(kk.y + qb.y, 0.f), ww.y, aB.y);
        aB.z = fmaf(fmaxf(kk.z + qb.z, 0.f), ww.z, aB.z);
        aB.w = fmaf(fmaxf(kk.w + qb.w, 0.f), ww.w, aB.w);
    }
    const bool vA = (j <= iA), vB = (j <= iB);
    float sA = vA ? ((aA.x + aA.y) + (aA.z + aA.w) + b2v) * 0.125f : -1e30f;
    float sB = vB ? ((aB.x + aB.y) + (aB.z + aB.w) + b2v) * 0.125f : -1e30f;

    // per-wave max (shfl only)
    float mAw = sA, mBw = sB;
    #pragma unroll
    for (int off = 32; off > 0; off >>= 1) {
        mAw = fmaxf(mAw, __shfl_xor(mAw, off));
        mBw = fmaxf(mBw, __shfl_xor(mBw, off));
    }
    const float ptA = vA ? __expf(sA - mAw) : 0.f;
    const float ptB = vB ? __expf(sB - mBw) : 0.f;
    float sAw = ptA, sBw = ptB;
    #pragma unroll
    for (int off = 32; off > 0; off >>= 1) {
        sAw += __shfl_xor(sAw, off);
        sBw += __shfl_xor(sBw, off);
    }
    const int w = tid >> 6;
    if ((tid & 63) == 0) wred4[w] = make_float4(mAw, sAw, mBw, sBw);
    __syncthreads();

    // global stats (every thread, 8 broadcast reads)
    float mA = -1e30f, mB = -1e30f;
    #pragma unroll
    for (int ww = 0; ww < 8; ++ww) {
        const float4 rd = wred4[ww];
        mA = fmaxf(mA, rd.x);
        mB = fmaxf(mB, rd.z);
    }
    float sumA = 0.f, sumB = 0.f;
    #pragma unroll
    for (int ww = 0; ww < 8; ++ww) {
        const float4 rd = wred4[ww];
        sumA = fmaf(rd.y, __expf(rd.x - mA), sumA);
        sumB = fmaf(rd.w, __expf(rd.z - mB), sumB);
    }
    // final p (rescale + 1/sum folded in)
    pA[j] = ptA * (__expf(mAw - mA) / sumA);
    pB[j] = ptB * (__expf(mBw - mB) / sumB);
    __syncthreads();

    // ---- PV for BOTH rows, shared x loads ----
    const int h = tid & 63;
    const int g = w;
    const float* xh = x + b * TLEN * CDIM + h;
    const float4* pA4 = (const float4*)pA;
    const float4* pB4 = (const float4*)pB;
    const int nj4 = (iB >> 2) + 1;
    float aA0 = 0.f, aA1 = 0.f, aA2 = 0.f, aA3 = 0.f;
    float aB0 = 0.f, aB1 = 0.f, aB2 = 0.f, aB3 = 0.f;
    for (int j4 = g; j4 < nj4; j4 += 8) {
        const float4 pa = pA4[j4];
        const float4 pb = pB4[j4];
        const int j0 = j4 * 4;
        const float x0 = xh[j0 * CDIM];
        const float x1 = xh[(j0 + 1) * CDIM];
        const float x2 = xh[(j0 + 2) * CDIM];
        const float x3 = xh[(j0 + 3) * CDIM];
        aA0 = fmaf(pa.x, x0, aA0); aB0 = fmaf(pb.x, x0, aB0);
        aA1 = fmaf(pa.y, x1, aA1); aB1 = fmaf(pb.y, x1, aB1);
        aA2 = fmaf(pa.z, x2, aA2); aB2 = fmaf(pb.z, x2, aB2);
        aA3 = fmaf(pa.w, x3, aA3); aB3 = fmaf(pb.w, x3, aB3);
    }
    pvs[0][g][h] = (aA0 + aA1) + (aA2 + aA3);
    pvs[1][g][h] = (aB0 + aB1) + (aB2 + aB3);
    __syncthreads();
    if (tid < 128) {
        const int rp = tid >> 6, hh = tid & 63;
        float o = pvs[rp][0][hh];
        #pragma unroll
        for (int ww = 1; ww < 8; ++ww) o += pvs[rp][ww][hh];
        o_s[rp][hh] = o;
    }
    __syncthreads();
    if (tid < 128) {                          // out[h] = o . Wv[h,:]
        const int rp = tid >> 6, hh = tid & 63;
        const int i  = rp ? iB : iA;
        const float4* wv = (const float4*)(Wv + hh * CDIM);
        const float4* o4 = (const float4*)o_s[rp];
        float4 a = make_float4(0.f, 0.f, 0.f, 0.f);
        #pragma unroll
        for (int c4 = 0; c4 < 16; ++c4) {
            const float4 wwv = wv[c4];
            const float4 oo = o4[c4];
            a.x = fmaf(oo.x, wwv.x, a.x); a.y = fmaf(oo.y, wwv.y, a.y);
            a.z = fmaf(oo.z, wwv.z, a.z); a.w = fmaf(oo.w, wwv.w, a.w);
        }
        out[(b * TLEN + i) * CDIM + hh] = (a.x + a.y) + (a.z + a.w);
    }
}

extern "C" void kernel_launch(void* const* d_in, const int* in_sizes, int n_in,
                              void* d_out, int out_size, void* d_ws, size_t ws_size,
                              hipStream_t stream)
{
    const float* x   = (const float*)d_in[0];
    const float* pos = (const float*)d_in[1];
    const float* W1  = (const float*)d_in[2];
    const float* b1  = (const float*)d_in[3];
    const float* W2  = (const float*)d_in[4];
    const float* b2  = (const float*)d_in[5];
    const float* Wv  = (const float*)d_in[6];
    float* out = (float*)d_out;

    float4* hkt4 = (float4*)d_ws;             // 256 KiB scratch

    hk_kernel<<<BDIM * TLEN / 16, 256, 0, stream>>>(x, pos, W1, hkt4);
    attn_kernel<<<BDIM * TLEN / 2, 512, 0, stream>>>(x, pos, W1, b1, W2, b2, Wv,
                                                     hkt4, out);
}